// Round 5
// baseline (1535.558 us; speedup 1.0000x reference)
//
#include <hip/hip_runtime.h>
#include <hip/hip_bf16.h>

#define VOCAB 12149
#define EMB 50
#define TAGS 9
#define HID 128
#define START_TOK 7
#define BSZ 256
#define TLEN 512
#define CH 64          // decoder chunk steps handed to projection wave
#define HPAD 132       // floats per hchunk row (16B-aligned: 132*4=528)

typedef float v2f __attribute__((ext_vector_type(2)));

__device__ __forceinline__ float tanh_fast(float x) {
  float e = __expf(2.0f * x);
  return 1.0f - 2.0f * __builtin_amdgcn_rcpf(e + 1.0f);
}

template<int CTRL>
__device__ __forceinline__ float dpp_mov(float x) {
  return __int_as_float(__builtin_amdgcn_update_dpp(
      0, __float_as_int(x), CTRL, 0xF, 0xF, true));
}
template<int CTRL>
__device__ __forceinline__ v2f dpp2(v2f x) {
  v2f r;
  r.x = dpp_mov<CTRL>(x.x);
  r.y = dpp_mov<CTRL>(x.y);
  return r;
}
#define DPP_XOR1 0xB1   // quad_perm [1,0,3,2]
#define DPP_XOR2 0x4E   // quad_perm [2,3,0,1]

// exw[v][j] = sum_e emb[v][e] * enc_Wx[e][j] + enc_b[j]
__global__ __launch_bounds__(128) void exw_kernel(
    const float* __restrict__ emb, const float* __restrict__ Wx,
    const float* __restrict__ bv, float* __restrict__ exw)
{
  __shared__ float wx_s[EMB * HID];
  __shared__ float emb_s[8 * EMB];
  const int tid = threadIdx.x;
  const int v0 = blockIdx.x * 8;
  for (int idx = tid; idx < EMB * HID; idx += 128) wx_s[idx] = Wx[idx];
  for (int idx = tid; idx < 8 * EMB; idx += 128) {
    int r = idx / EMB;
    int e = idx - r * EMB;
    int v = v0 + r;
    emb_s[idx] = (v < VOCAB) ? emb[v * EMB + e] : 0.0f;
  }
  __syncthreads();
  const float bj = bv[tid];
  for (int r = 0; r < 8; ++r) {
    int v = v0 + r;
    if (v >= VOCAB) break;
    float acc = bj;
#pragma unroll
    for (int e = 0; e < EMB; ++e) acc += emb_s[r * EMB + e] * wx_s[e * HID + tid];
    exw[v * HID + tid] = acc;
  }
}

// Single-wave recurrence step: lane (l2=lane&3, jg=lane>>2).
// Slot m <-> output pair p = m^l2 (j = 8jg+2p); k-range [32*l2, +32), read
// rotated by (r+2*l2)&7 for bank-conflict freedom. After the quad
// reduce-scatter, lane owns exactly h[2*lane .. 2*lane+1].
__device__ __forceinline__ v2f rnn_dot(const float* __restrict__ h_s, int l2,
                                       const v2f (&wL)[8][2][4],
                                       const v2f (&wH)[8][2][4]) {
  v2f aL[4], aH[4];
#pragma unroll
  for (int m = 0; m < 4; ++m) { aL[m] = v2f{0.f, 0.f}; aH[m] = v2f{0.f, 0.f}; }
#pragma unroll
  for (int r = 0; r < 8; ++r) {
    const float4 hv = *(const float4*)&h_s[32 * l2 + 4 * ((r + 2 * l2) & 7)];
    const v2f h2a = {hv.x, hv.y};
    const v2f h2b = {hv.z, hv.w};
#pragma unroll
    for (int m = 0; m < 4; ++m) {
      aL[m] = __builtin_elementwise_fma(h2a, wL[r][0][m], aL[m]);
      aH[m] = __builtin_elementwise_fma(h2a, wH[r][0][m], aH[m]);
      aL[m] = __builtin_elementwise_fma(h2b, wL[r][1][m], aL[m]);
      aH[m] = __builtin_elementwise_fma(h2b, wH[r][1][m], aH[m]);
    }
  }
  v2f u[4];
#pragma unroll
  for (int m = 0; m < 4; ++m)
    u[m] = v2f{aL[m].x + aL[m].y, aH[m].x + aH[m].y};
  u[0] += dpp2<DPP_XOR1>(u[1]);
  u[2] += dpp2<DPP_XOR1>(u[3]);
  u[0] += dpp2<DPP_XOR2>(u[2]);
  return u[0];
}

// One WG (128 thr = 2 waves) per batch row. Wave 0: recurrence, barrier-free
// (single-wave, in-order LDS). Wave 1: async projection consumer.
__global__ __launch_bounds__(128, 1) void rnn_kernel(
    const int* __restrict__ inputs, const int* __restrict__ labels,
    const float* __restrict__ exw,
    const float* __restrict__ encWh,
    const float* __restrict__ dembG, const float* __restrict__ decWx,
    const float* __restrict__ decWh, const float* __restrict__ decb,
    const float* __restrict__ W, const float* __restrict__ bout,
    float* __restrict__ out)
{
  __shared__ __align__(16) float h_s[HID];
  __shared__ __align__(16) float dxw_s[TAGS * HID];
  __shared__ __align__(16) float Wt_s[TAGS][HID];
  __shared__ __align__(16) float hchunk_s[2][CH][HPAD];
  __shared__ int tok_s[TLEN];
  __shared__ int lab_s[TLEN];
  __shared__ int flag_s;
  __shared__ int ack_s;

  const int tid = threadIdx.x;
  const int wid = tid >> 6;
  const int lane = tid & 63;
  const int bidx = blockIdx.x;

  // ---- staging (both waves) ----
  for (int idx = tid; idx < TLEN; idx += 128) {
    tok_s[idx] = inputs[bidx * TLEN + idx];
    lab_s[idx] = labels[bidx * TLEN + idx];
  }
  for (int idx = tid; idx < TAGS * HID; idx += 128) {
    int tag = idx >> 7;
    int j2 = idx & 127;
    float acc = decb[j2];
#pragma unroll
    for (int e = 0; e < EMB; ++e) acc += dembG[tag * EMB + e] * decWx[e * HID + j2];
    dxw_s[idx] = acc;
    Wt_s[tag][j2] = W[j2 * TAGS + tag];   // W^T for projection wave
  }
  if (tid < 64) { h_s[2 * tid] = 0.0f; h_s[2 * tid + 1] = 0.0f; }
  if (tid == 0) { flag_s = 0; ack_s = 0; }
  __syncthreads();   // the only barrier in the kernel

  if (wid == 0) {
    // ================= recurrence wave =================
    const int l2 = lane & 3;
    const int jg = lane >> 2;

    v2f wL[8][2][4], wH[8][2][4];
#pragma unroll
    for (int r = 0; r < 8; ++r) {
      const int kb = 32 * l2 + 4 * ((r + 2 * l2) & 7);
#pragma unroll
      for (int p = 0; p < 2; ++p)
#pragma unroll
        for (int m = 0; m < 4; ++m) {
          const int jlo = 8 * jg + 2 * (m ^ l2);
          const int k0 = kb + 2 * p;
          wL[r][p][m] = v2f{encWh[k0 * HID + jlo],     encWh[(k0 + 1) * HID + jlo]};
          wH[r][p][m] = v2f{encWh[k0 * HID + jlo + 1], encWh[(k0 + 1) * HID + jlo + 1]};
        }
    }

    const float* exw_q = exw + 2 * lane;
    v2f xv0 = *(const v2f*)&exw_q[tok_s[0] * HID];
    v2f xv1 = *(const v2f*)&exw_q[tok_s[1] * HID];
    v2f xv2 = *(const v2f*)&exw_q[tok_s[2] * HID];
    v2f xv3 = *(const v2f*)&exw_q[tok_s[3] * HID];

    // ---- encoder ----
#pragma unroll 4
    for (int t = 0; t < TLEN; ++t) {
      int tn = (t + 4 < TLEN) ? t + 4 : TLEN - 1;
      v2f xvn = *(const v2f*)&exw_q[tok_s[tn] * HID];
      v2f u = rnn_dot(h_s, l2, wL, wH) + xv0;
      v2f hn;
      hn.x = tanh_fast(u.x);
      hn.y = tanh_fast(u.y);
      *(v2f*)&h_s[2 * lane] = hn;
      xv0 = xv1; xv1 = xv2; xv2 = xv3; xv3 = xvn;
    }

    // ---- decoder weights into the same registers ----
#pragma unroll
    for (int r = 0; r < 8; ++r) {
      const int kb = 32 * l2 + 4 * ((r + 2 * l2) & 7);
#pragma unroll
      for (int p = 0; p < 2; ++p)
#pragma unroll
        for (int m = 0; m < 4; ++m) {
          const int jlo = 8 * jg + 2 * (m ^ l2);
          const int k0 = kb + 2 * p;
          wL[r][p][m] = v2f{decWh[k0 * HID + jlo],     decWh[(k0 + 1) * HID + jlo]};
          wH[r][p][m] = v2f{decWh[k0 * HID + jlo + 1], decWh[(k0 + 1) * HID + jlo + 1]};
        }
    }

    // ---- decoder ----
#pragma unroll 4
    for (int t = 0; t < TLEN; ++t) {
      if ((t & (CH - 1)) == 0) {
        int c = t >> 6;
        if (c >= 2) {
          while (*(volatile int*)&ack_s < c - 1) __builtin_amdgcn_s_sleep(2);
          __asm volatile("" ::: "memory");
        }
      }
      int lab = (t == 0) ? START_TOK : lab_s[t - 1];
      v2f xv = *(const v2f*)&dxw_s[lab * HID + 2 * lane];
      v2f u = rnn_dot(h_s, l2, wL, wH) + xv;
      v2f hn;
      hn.x = tanh_fast(u.x);
      hn.y = tanh_fast(u.y);
      *(v2f*)&h_s[2 * lane] = hn;
      *(v2f*)&hchunk_s[(t >> 6) & 1][t & (CH - 1)][2 * lane] = hn;
      if ((t & (CH - 1)) == CH - 1) {
        __asm volatile("" ::: "memory");
        if (lane == 0) *(volatile int*)&flag_s = (t >> 6) + 1;
      }
    }
  } else {
    // ================= projection wave =================
    float bb[TAGS];
#pragma unroll
    for (int o = 0; o < TAGS; ++o) bb[o] = bout[o];

    for (int c = 0; c < TLEN / CH; ++c) {
      while (*(volatile int*)&flag_s < c + 1) __builtin_amdgcn_s_sleep(8);
      __asm volatile("" ::: "memory");
      const float* hrow = &hchunk_s[c & 1][lane][0];
      float oa[TAGS];
#pragma unroll
      for (int o = 0; o < TAGS; ++o) oa[o] = 0.0f;
#pragma unroll
      for (int hb = 0; hb < 2; ++hb) {
        float4 hv[16];
#pragma unroll
        for (int c4 = 0; c4 < 16; ++c4)
          hv[c4] = *(const float4*)&hrow[hb * 64 + 4 * c4];
#pragma unroll
        for (int o = 0; o < TAGS; ++o) {
          v2f acc = {0.f, 0.f};
#pragma unroll
          for (int c4 = 0; c4 < 16; ++c4) {
            const float4 wv4 = *(const float4*)&Wt_s[o][hb * 64 + 4 * c4];
            acc = __builtin_elementwise_fma(v2f{hv[c4].x, hv[c4].y},
                                            v2f{wv4.x, wv4.y}, acc);
            acc = __builtin_elementwise_fma(v2f{hv[c4].z, hv[c4].w},
                                            v2f{wv4.z, wv4.w}, acc);
          }
          oa[o] += acc.x + acc.y;
        }
      }
      int t = c * CH + lane;
      float* op = &out[(bidx * TLEN + t) * TAGS];
#pragma unroll
      for (int o = 0; o < TAGS; ++o) op[o] = oa[o] + bb[o];
      __asm volatile("" ::: "memory");
      if (lane == 0) *(volatile int*)&ack_s = c + 1;
    }
  }
}

extern "C" void kernel_launch(void* const* d_in, const int* in_sizes, int n_in,
                              void* d_out, int out_size, void* d_ws, size_t ws_size,
                              hipStream_t stream) {
  const int* inputs   = (const int*)d_in[0];
  const int* labels   = (const int*)d_in[1];
  const float* emb    = (const float*)d_in[2];
  const float* encWx  = (const float*)d_in[3];
  const float* encWh  = (const float*)d_in[4];
  const float* encb   = (const float*)d_in[5];
  const float* demb   = (const float*)d_in[6];
  const float* decWx  = (const float*)d_in[7];
  const float* decWh  = (const float*)d_in[8];
  const float* decb   = (const float*)d_in[9];
  const float* W      = (const float*)d_in[10];
  const float* bo     = (const float*)d_in[11];
  float* out = (float*)d_out;

  float* exw = (float*)d_ws;  // VOCAB*HID floats = 6.22 MB

  exw_kernel<<<(VOCAB + 7) / 8, 128, 0, stream>>>(emb, encWx, encb, exw);
  rnn_kernel<<<BSZ, 128, 0, stream>>>(inputs, labels, exw, encWh,
                                      demb, decWx, decWh, decb, W, bo, out);
}

// Round 6
// 549.595 us; speedup vs baseline: 2.7940x; 2.7940x over previous
//
#include <hip/hip_runtime.h>
#include <hip/hip_bf16.h>

#define VOCAB 12149
#define EMB 50
#define TAGS 9
#define HID 128
#define START_TOK 7
#define BSZ 256
#define TLEN 512

typedef float v2f __attribute__((ext_vector_type(2)));
typedef _Float16 h2 __attribute__((ext_vector_type(2)));

__device__ __forceinline__ float tanh_fast(float x) {
  float e = __expf(2.0f * x);
  return 1.0f - 2.0f * __builtin_amdgcn_rcpf(e + 1.0f);
}

__device__ __forceinline__ float fdot2(h2 a, h2 b, float c) {
#if __has_builtin(__builtin_amdgcn_fdot2)
  return __builtin_amdgcn_fdot2(a, b, c, false);
#else
  return c + (float)a.x * (float)b.x + (float)a.y * (float)b.y;
#endif
}

template<int CTRL>
__device__ __forceinline__ float dpp_mov(float x) {
  return __int_as_float(__builtin_amdgcn_update_dpp(
      0, __float_as_int(x), CTRL, 0xF, 0xF, true));
}
#define DPP_XOR1 0xB1
#define DPP_XOR2 0x4E
#define DPP_ROR4 0x124
#define DPP_ROR8 0x128

// exw[v][j] = sum_e emb[v][e] * enc_Wx[e][j] + enc_b[j]
__global__ __launch_bounds__(128) void exw_kernel(
    const float* __restrict__ emb, const float* __restrict__ Wx,
    const float* __restrict__ bv, float* __restrict__ exw)
{
  __shared__ float wx_s[EMB * HID];
  __shared__ float emb_s[8 * EMB];
  const int tid = threadIdx.x;
  const int v0 = blockIdx.x * 8;
  for (int idx = tid; idx < EMB * HID; idx += 128) wx_s[idx] = Wx[idx];
  for (int idx = tid; idx < 8 * EMB; idx += 128) {
    int r = idx / EMB;
    int e = idx - r * EMB;
    int v = v0 + r;
    emb_s[idx] = (v < VOCAB) ? emb[v * EMB + e] : 0.0f;
  }
  __syncthreads();
  const float bj = bv[tid];
  for (int r = 0; r < 8; ++r) {
    int v = v0 + r;
    if (v >= VOCAB) break;
    float acc = bj;
#pragma unroll
    for (int e = 0; e < EMB; ++e) acc += emb_s[r * EMB + e] * wx_s[e * HID + tid];
    exw[v * HID + tid] = acc;
  }
}

// Single wave (64 threads) per batch row. Lane owns outputs {2l, 2l+1} over
// the FULL k range: no cross-lane reduce, no barriers. Weights f16-packed
// (128 VGPRs), h in LDS as 64 half2 (broadcast reads), fdot2 f32-accumulate.
template<int FUSE>
__global__ __launch_bounds__(64, 1) void rnn_kernel(
    const int* __restrict__ inputs, const int* __restrict__ labels,
    const float* __restrict__ exw,
    const float* __restrict__ encWh,
    const float* __restrict__ dembG, const float* __restrict__ decWx,
    const float* __restrict__ decWh, const float* __restrict__ decb,
    const float* __restrict__ W, const float* __restrict__ bout,
    unsigned int* __restrict__ hws, float* __restrict__ out)
{
  __shared__ __align__(16) h2 hh_s[64];          // h as f16 pairs (256 B)
  __shared__ __align__(16) float dxw_s[TAGS * HID];
  __shared__ int tok_s[TLEN];
  __shared__ int lab_s[TLEN];

  const int lane = threadIdx.x;   // 0..63 (one wave)
  const int bidx = blockIdx.x;
  const int j0 = 2 * lane;

  // ---- staging (single wave; DS in-order => no barrier anywhere) ----
  for (int idx = lane; idx < TLEN; idx += 64) {
    tok_s[idx] = inputs[bidx * TLEN + idx];
    lab_s[idx] = labels[bidx * TLEN + idx];
  }
  for (int task = lane; task < TAGS * HID; task += 64) {
    int tag = task >> 7;
    int j2 = task & 127;
    float acc = decb[j2];
#pragma unroll
    for (int e = 0; e < EMB; ++e) acc += dembG[tag * EMB + e] * decWx[e * HID + j2];
    dxw_s[task] = acc;
  }
  hh_s[lane] = h2{(_Float16)0.0f, (_Float16)0.0f};

  // ---- encoder weights, f16-packed along k: wA/wB[k2] = Wh[2k2..2k2+1][j] ----
  h2 wA[64], wB[64];
#pragma unroll
  for (int k2 = 0; k2 < 64; ++k2) {
    float a0 = encWh[(2 * k2) * HID + j0];
    float a1 = encWh[(2 * k2 + 1) * HID + j0];
    float b0 = encWh[(2 * k2) * HID + j0 + 1];
    float b1 = encWh[(2 * k2 + 1) * HID + j0 + 1];
    wA[k2] = h2{(_Float16)a0, (_Float16)a1};
    wB[k2] = h2{(_Float16)b0, (_Float16)b1};
  }

  // ---- fused-projection registers (only used when FUSE) ----
  float wf0[TAGS], wf1[TAGS], bo_r[TAGS];
  if (FUSE) {
#pragma unroll
    for (int o = 0; o < TAGS; ++o) {
      wf0[o] = W[(j0) * TAGS + o];
      wf1[o] = W[(j0 + 1) * TAGS + o];
      bo_r[o] = bout[o];
    }
  }

  const float* exw_q = exw + j0;
  v2f xv0 = *(const v2f*)&exw_q[tok_s[0] * HID];
  v2f xv1 = *(const v2f*)&exw_q[tok_s[1] * HID];
  v2f xv2 = *(const v2f*)&exw_q[tok_s[2] * HID];
  v2f xv3 = *(const v2f*)&exw_q[tok_s[3] * HID];

  // ======== encoder ========
#pragma unroll 4
  for (int t = 0; t < TLEN; ++t) {
    int tn = (t + 4 < TLEN) ? t + 4 : TLEN - 1;
    v2f xvn = *(const v2f*)&exw_q[tok_s[tn] * HID];

    const uint4* hp = (const uint4*)hh_s;   // same addr across lanes: broadcast
    float a0 = 0.f, a1 = 0.f, b0 = 0.f, b1 = 0.f;
#pragma unroll
    for (int c = 0; c < 16; ++c) {
      uint4 u = hp[c];
      h2 p0 = __builtin_bit_cast(h2, u.x);
      h2 p1 = __builtin_bit_cast(h2, u.y);
      h2 p2 = __builtin_bit_cast(h2, u.z);
      h2 p3 = __builtin_bit_cast(h2, u.w);
      a0 = fdot2(p0, wA[4 * c + 0], a0); b0 = fdot2(p0, wB[4 * c + 0], b0);
      a1 = fdot2(p1, wA[4 * c + 1], a1); b1 = fdot2(p1, wB[4 * c + 1], b1);
      a0 = fdot2(p2, wA[4 * c + 2], a0); b0 = fdot2(p2, wB[4 * c + 2], b0);
      a1 = fdot2(p3, wA[4 * c + 3], a1); b1 = fdot2(p3, wB[4 * c + 3], b1);
    }
    float hx = tanh_fast(a0 + a1 + xv0.x);
    float hy = tanh_fast(b0 + b1 + xv0.y);
    hh_s[lane] = h2{(_Float16)hx, (_Float16)hy};
    xv0 = xv1; xv1 = xv2; xv2 = xv3; xv3 = xvn;
  }

  // ---- decoder weights into the same registers ----
#pragma unroll
  for (int k2 = 0; k2 < 64; ++k2) {
    float a0 = decWh[(2 * k2) * HID + j0];
    float a1 = decWh[(2 * k2 + 1) * HID + j0];
    float b0 = decWh[(2 * k2) * HID + j0 + 1];
    float b1 = decWh[(2 * k2 + 1) * HID + j0 + 1];
    wA[k2] = h2{(_Float16)a0, (_Float16)a1};
    wB[k2] = h2{(_Float16)b0, (_Float16)b1};
  }

  // ======== decoder ========
  unsigned int* hrow = hws + (bidx * TLEN) * 64 + lane;
#pragma unroll 2
  for (int t = 0; t < TLEN; ++t) {
    int lab = (t == 0) ? START_TOK : lab_s[t - 1];
    v2f xv = *(const v2f*)&dxw_s[lab * HID + j0];

    const uint4* hp = (const uint4*)hh_s;
    float a0 = 0.f, a1 = 0.f, b0 = 0.f, b1 = 0.f;
#pragma unroll
    for (int c = 0; c < 16; ++c) {
      uint4 u = hp[c];
      h2 p0 = __builtin_bit_cast(h2, u.x);
      h2 p1 = __builtin_bit_cast(h2, u.y);
      h2 p2 = __builtin_bit_cast(h2, u.z);
      h2 p3 = __builtin_bit_cast(h2, u.w);
      a0 = fdot2(p0, wA[4 * c + 0], a0); b0 = fdot2(p0, wB[4 * c + 0], b0);
      a1 = fdot2(p1, wA[4 * c + 1], a1); b1 = fdot2(p1, wB[4 * c + 1], b1);
      a0 = fdot2(p2, wA[4 * c + 2], a0); b0 = fdot2(p2, wB[4 * c + 2], b0);
      a1 = fdot2(p3, wA[4 * c + 3], a1); b1 = fdot2(p3, wB[4 * c + 3], b1);
    }
    float hx = tanh_fast(a0 + a1 + xv.x);
    float hy = tanh_fast(b0 + b1 + xv.y);
    h2 hn = h2{(_Float16)hx, (_Float16)hy};
    hh_s[lane] = hn;

    if (!FUSE) {
      hrow[t * 64] = __builtin_bit_cast(unsigned int, hn);  // fire-and-forget
    } else {
      // fused projection: p[o] = sum over lanes of hx*W[2l][o] + hy*W[2l+1][o]
      float p[TAGS];
#pragma unroll
      for (int o = 0; o < TAGS; ++o) {
        float v = hx * wf0[o] + hy * wf1[o];
        v += dpp_mov<DPP_XOR1>(v);
        v += dpp_mov<DPP_XOR2>(v);
        v += dpp_mov<DPP_ROR4>(v);
        v += dpp_mov<DPP_ROR8>(v);
        v += __shfl_xor(v, 16);
        v += __shfl_xor(v, 32);
        p[o] = v;
      }
      if (lane == 0) {
        float* op = &out[(bidx * TLEN + t) * TAGS];
#pragma unroll
        for (int o = 0; o < TAGS; ++o) op[o] = p[o] + bo_r[o];
      }
    }
  }
}

// out[t][o] = h[t] @ W + b, h stored as 64 half2 per row
__global__ __launch_bounds__(256) void proj_kernel(
    const unsigned int* __restrict__ hws, const float* __restrict__ W,
    const float* __restrict__ bout, float* __restrict__ out)
{
  __shared__ float Wt_s[TAGS][HID];
  __shared__ float bo_s[TAGS];
  const int tid = threadIdx.x;
  for (int idx = tid; idx < TAGS * HID; idx += 256) {
    int o = idx >> 7;
    int j2 = idx & 127;
    Wt_s[o][j2] = W[j2 * TAGS + o];
  }
  if (tid < TAGS) bo_s[tid] = bout[tid];
  __syncthreads();

  const int gt = blockIdx.x * 256 + tid;       // 0 .. B*T-1
  const uint4* hrow = (const uint4*)(hws + gt * 64);
  float acc[TAGS];
#pragma unroll
  for (int o = 0; o < TAGS; ++o) acc[o] = bo_s[o];
#pragma unroll
  for (int c = 0; c < 16; ++c) {
    uint4 u = hrow[c];
    h2 p0 = __builtin_bit_cast(h2, u.x);
    h2 p1 = __builtin_bit_cast(h2, u.y);
    h2 p2 = __builtin_bit_cast(h2, u.z);
    h2 p3 = __builtin_bit_cast(h2, u.w);
    float h0 = (float)p0.x, h1 = (float)p0.y, h2f = (float)p1.x, h3 = (float)p1.y;
    float h4 = (float)p2.x, h5 = (float)p2.y, h6 = (float)p3.x, h7 = (float)p3.y;
#pragma unroll
    for (int o = 0; o < TAGS; ++o) {
      const float* wr = &Wt_s[o][8 * c];
      acc[o] += h0 * wr[0] + h1 * wr[1] + h2f * wr[2] + h3 * wr[3]
              + h4 * wr[4] + h5 * wr[5] + h6 * wr[6] + h7 * wr[7];
    }
  }
  float* op = &out[gt * TAGS];
#pragma unroll
  for (int o = 0; o < TAGS; ++o) op[o] = acc[o];
}

extern "C" void kernel_launch(void* const* d_in, const int* in_sizes, int n_in,
                              void* d_out, int out_size, void* d_ws, size_t ws_size,
                              hipStream_t stream) {
  const int* inputs   = (const int*)d_in[0];
  const int* labels   = (const int*)d_in[1];
  const float* emb    = (const float*)d_in[2];
  const float* encWx  = (const float*)d_in[3];
  const float* encWh  = (const float*)d_in[4];
  const float* encb   = (const float*)d_in[5];
  const float* demb   = (const float*)d_in[6];
  const float* decWx  = (const float*)d_in[7];
  const float* decWh  = (const float*)d_in[8];
  const float* decb   = (const float*)d_in[9];
  const float* W      = (const float*)d_in[10];
  const float* bo     = (const float*)d_in[11];
  float* out = (float*)d_out;

  const size_t exw_floats = (size_t)VOCAB * HID;               // 6.22 MB
  const size_t h_bytes = (size_t)BSZ * TLEN * 64 * 4;          // 33.5 MB
  float* exw = (float*)d_ws;
  unsigned int* hws = (unsigned int*)d_ws + exw_floats;
  const bool fits = ws_size >= exw_floats * 4 + h_bytes;

  exw_kernel<<<(VOCAB + 7) / 8, 128, 0, stream>>>(emb, encWx, encb, exw);
  if (fits) {
    rnn_kernel<0><<<BSZ, 64, 0, stream>>>(inputs, labels, exw, encWh,
                                          demb, decWx, decWh, decb, W, bo,
                                          hws, out);
    proj_kernel<<<(BSZ * TLEN) / 256, 256, 0, stream>>>(hws, W, bo, out);
  } else {
    rnn_kernel<1><<<BSZ, 64, 0, stream>>>(inputs, labels, exw, encWh,
                                          demb, decWx, decWh, decb, W, bo,
                                          hws, out);
  }
}

// Round 8
// 372.231 us; speedup vs baseline: 4.1253x; 1.4765x over previous
//
#include <hip/hip_runtime.h>
#include <hip/hip_bf16.h>

#define VOCAB 12149
#define EMB 50
#define TAGS 9
#define HID 128
#define START_TOK 7
#define BSZ 256
#define TLEN 512

typedef float v2f __attribute__((ext_vector_type(2)));
typedef _Float16 f16x2 __attribute__((ext_vector_type(2)));

__device__ __forceinline__ float tanh_fast(float x) {
  float e = __expf(2.0f * x);
  return 1.0f - 2.0f * __builtin_amdgcn_rcpf(e + 1.0f);
}

template<int CTRL>
__device__ __forceinline__ float dpp_mov(float x) {
  return __int_as_float(__builtin_amdgcn_update_dpp(
      0, __float_as_int(x), CTRL, 0xF, 0xF, true));
}
#define DPP_XOR1 0xB1   // quad_perm [1,0,3,2]

// exw[v][j] = sum_e emb[v][e] * enc_Wx[e][j] + enc_b[j]
__global__ __launch_bounds__(128) void exw_kernel(
    const float* __restrict__ emb, const float* __restrict__ Wx,
    const float* __restrict__ bv, float* __restrict__ exw)
{
  __shared__ float wx_s[EMB * HID];
  __shared__ float emb_s[8 * EMB];
  const int tid = threadIdx.x;
  const int v0 = blockIdx.x * 8;
  for (int idx = tid; idx < EMB * HID; idx += 128) wx_s[idx] = Wx[idx];
  for (int idx = tid; idx < 8 * EMB; idx += 128) {
    int r = idx / EMB;
    int e = idx - r * EMB;
    int v = v0 + r;
    emb_s[idx] = (v < VOCAB) ? emb[v * EMB + e] : 0.0f;
  }
  __syncthreads();
  const float bj = bv[tid];
  for (int r = 0; r < 8; ++r) {
    int v = v0 + r;
    if (v >= VOCAB) break;
    float acc = bj;
#pragma unroll
    for (int e = 0; e < EMB; ++e) acc += emb_s[r * EMB + e] * wx_s[e * HID + tid];
    exw[v * HID + tid] = acc;
  }
}

// One WG (128 thr = 2 waves) per batch row. Thread i owns h[i]; pair
// (i&~1, i|1) k-splits (q=i&1 -> k in [64q,64q+64)). Scalar v_fma_f32
// MACs (full-rate), weights 128 f32 VGPRs, pair-reduce = 1 DPP xor1,
// one 2-wave barrier per step.
__global__ __launch_bounds__(128, 1) void rnn_kernel(
    const int* __restrict__ inputs, const int* __restrict__ labels,
    const float* __restrict__ exw,
    const float* __restrict__ encWh,
    const float* __restrict__ dembG, const float* __restrict__ decWx,
    const float* __restrict__ decWh, const float* __restrict__ decb,
    unsigned short* __restrict__ hws16)
{
  __shared__ __align__(16) float h_s[2][HID];
  __shared__ __align__(16) float dxw_s[TAGS * HID];
  __shared__ int tok_s[TLEN];
  __shared__ int lab_s[TLEN];

  const int tid = threadIdx.x;    // 0..127
  const int q = tid & 1;          // k-half
  const int jE = tid & ~1;        // even column of the owned pair
  const int bidx = blockIdx.x;

  for (int idx = tid; idx < TLEN; idx += 128) {
    tok_s[idx] = inputs[bidx * TLEN + idx];
    lab_s[idx] = labels[bidx * TLEN + idx];
  }
  for (int task = tid; task < TAGS * HID; task += 128) {
    int tag = task >> 7;
    int j2 = task & 127;
    float acc = decb[j2];
#pragma unroll
    for (int e = 0; e < EMB; ++e) acc += dembG[tag * EMB + e] * decWx[e * HID + j2];
    dxw_s[task] = acc;
  }
  h_s[0][tid] = 0.0f;

  v2f wv[64];
#pragma unroll
  for (int kk = 0; kk < 64; ++kk)
    wv[kk] = *(const v2f*)&encWh[(64 * q + kk) * HID + jE];
  __syncthreads();

  const float* exw_i = exw + tid;
  int cur = 0;

  float xv0 = exw_i[tok_s[0] * HID];
  float xv1 = exw_i[tok_s[1] * HID];
  float xv2 = exw_i[tok_s[2] * HID];
  float xv3 = exw_i[tok_s[3] * HID];

  // ======== encoder ========
#pragma unroll 4
  for (int t = 0; t < TLEN; ++t) {
    int tn = (t + 4 < TLEN) ? t + 4 : TLEN - 1;
    float xvn = exw_i[tok_s[tn] * HID];

    const float* hb = &h_s[cur][64 * q];
    float aE0 = 0.f, aE1 = 0.f, aO0 = 0.f, aO1 = 0.f;
#pragma unroll
    for (int c = 0; c < 16; ++c) {
      float4 hv = *(const float4*)&hb[4 * c];
      aE0 += hv.x * wv[4 * c + 0].x;  aO0 += hv.x * wv[4 * c + 0].y;
      aE1 += hv.y * wv[4 * c + 1].x;  aO1 += hv.y * wv[4 * c + 1].y;
      aE0 += hv.z * wv[4 * c + 2].x;  aO0 += hv.z * wv[4 * c + 2].y;
      aE1 += hv.w * wv[4 * c + 3].x;  aO1 += hv.w * wv[4 * c + 3].y;
    }
    float aE = aE0 + aE1, aO = aO0 + aO1;
    float keep = q ? aO : aE;
    float send = q ? aE : aO;
    float v = keep + dpp_mov<DPP_XOR1>(send);
    float hn = tanh_fast(v + xv0);
    h_s[cur ^ 1][tid] = hn;
    __syncthreads();
    cur ^= 1;
    xv0 = xv1; xv1 = xv2; xv2 = xv3; xv3 = xvn;
  }

  // ---- decoder weights ----
#pragma unroll
  for (int kk = 0; kk < 64; ++kk)
    wv[kk] = *(const v2f*)&decWh[(64 * q + kk) * HID + jE];

  // ======== decoder ========
  unsigned short* hrow = hws16 + (size_t)(bidx * TLEN) * HID + tid;
  float xvD = dxw_s[START_TOK * HID + tid];
#pragma unroll 2
  for (int t = 0; t < TLEN; ++t) {
    int labn = lab_s[t];                       // dec_in[t+1] = label[t]
    float xvDn = dxw_s[labn * HID + tid];      // prefetch next step's xv

    const float* hb = &h_s[cur][64 * q];
    float aE0 = 0.f, aE1 = 0.f, aO0 = 0.f, aO1 = 0.f;
#pragma unroll
    for (int c = 0; c < 16; ++c) {
      float4 hv = *(const float4*)&hb[4 * c];
      aE0 += hv.x * wv[4 * c + 0].x;  aO0 += hv.x * wv[4 * c + 0].y;
      aE1 += hv.y * wv[4 * c + 1].x;  aO1 += hv.y * wv[4 * c + 1].y;
      aE0 += hv.z * wv[4 * c + 2].x;  aO0 += hv.z * wv[4 * c + 2].y;
      aE1 += hv.w * wv[4 * c + 3].x;  aO1 += hv.w * wv[4 * c + 3].y;
    }
    float aE = aE0 + aE1, aO = aO0 + aO1;
    float keep = q ? aO : aE;
    float send = q ? aE : aO;
    float v = keep + dpp_mov<DPP_XOR1>(send);
    float hn = tanh_fast(v + xvD);
    h_s[cur ^ 1][tid] = hn;
    hrow[(size_t)t * HID] =
        __builtin_bit_cast(unsigned short, (_Float16)hn);
    __syncthreads();
    cur ^= 1;
    xvD = xvDn;
  }
}

// out[t][o] = h[t] @ W + b; h stored as 128 f16 per row
__global__ __launch_bounds__(256) void proj_kernel(
    const unsigned short* __restrict__ hws16, const float* __restrict__ W,
    const float* __restrict__ bout, float* __restrict__ out)
{
  __shared__ float Wt_s[TAGS][HID];
  __shared__ float bo_s[TAGS];
  const int tid = threadIdx.x;
  for (int idx = tid; idx < TAGS * HID; idx += 256) {
    int o = idx >> 7;
    int j2 = idx & 127;
    Wt_s[o][j2] = W[j2 * TAGS + o];
  }
  if (tid < TAGS) bo_s[tid] = bout[tid];
  __syncthreads();

  const int gt = blockIdx.x * 256 + tid;       // 0 .. B*T-1
  const uint2* hrow = (const uint2*)(hws16 + (size_t)gt * HID);
  float acc[TAGS];
#pragma unroll
  for (int o = 0; o < TAGS; ++o) acc[o] = bo_s[o];
#pragma unroll
  for (int c = 0; c < 32; ++c) {               // 32 chunks x 4 f16 = 128 = HID
    uint2 u = hrow[c];
    f16x2 p0 = __builtin_bit_cast(f16x2, u.x);
    f16x2 p1 = __builtin_bit_cast(f16x2, u.y);
    float h0 = (float)p0.x, h1 = (float)p0.y;
    float h2v = (float)p1.x, h3 = (float)p1.y;
#pragma unroll
    for (int o = 0; o < TAGS; ++o) {
      const float* wr = &Wt_s[o][4 * c];
      acc[o] += h0 * wr[0] + h1 * wr[1] + h2v * wr[2] + h3 * wr[3];
    }
  }
  float* op = &out[(size_t)gt * TAGS];
#pragma unroll
  for (int o = 0; o < TAGS; ++o) op[o] = acc[o];
}

extern "C" void kernel_launch(void* const* d_in, const int* in_sizes, int n_in,
                              void* d_out, int out_size, void* d_ws, size_t ws_size,
                              hipStream_t stream) {
  const int* inputs   = (const int*)d_in[0];
  const int* labels   = (const int*)d_in[1];
  const float* emb    = (const float*)d_in[2];
  const float* encWx  = (const float*)d_in[3];
  const float* encWh  = (const float*)d_in[4];
  const float* encb   = (const float*)d_in[5];
  const float* demb   = (const float*)d_in[6];
  const float* decWx  = (const float*)d_in[7];
  const float* decWh  = (const float*)d_in[8];
  const float* decb   = (const float*)d_in[9];
  const float* W      = (const float*)d_in[10];
  const float* bo     = (const float*)d_in[11];
  float* out = (float*)d_out;

  const size_t exw_floats = (size_t)VOCAB * HID;                 // 6.22 MB
  float* exw = (float*)d_ws;
  unsigned short* hws16 = (unsigned short*)((float*)d_ws + exw_floats);
  // needed: 6.22 MB + B*T*HID*2 = 23 MB total (ws proven >= 40 MB in round 6)

  exw_kernel<<<(VOCAB + 7) / 8, 128, 0, stream>>>(emb, encWx, encb, exw);
  rnn_kernel<<<BSZ, 128, 0, stream>>>(inputs, labels, exw, encWh,
                                      demb, decWx, decWh, decb, hws16);
  proj_kernel<<<(BSZ * TLEN) / 256, 256, 0, stream>>>(hws16, W, bo, out);
}